// Round 4
// baseline (545.137 us; speedup 1.0000x reference)
//
#include <hip/hip_runtime.h>
#include <math.h>

// QURNN cell, MI355X gfx950, f32 I/O. B=4096, D_IN=D_H=1024.
//
// Round 4: all 6 GEMMs single-f16 (no hi/lo split). The discrete leap
// branch (t = ratio*relu(tc+ut)-1 <= 0) is protected by a boundary fixup:
// cell flags |t| < DELTA=0.02 (f16-GEMM error is ~1.5e-2 at 10 sigma) into a
// compacted list; fixup recomputes ratio/ut exactly (f32 dots) for flagged
// elements and rewrites time/excited/hup. Writes are per-element idempotent
// -> deterministic despite atomic list order.
//
// Dispatches: convert -> gemm5 (Wt,Wa,Hw,Tr,Ei) -> cell -> fixup -> eh
// GEMM: 128x128 tile, BK=32, 16x16x32 f16 MFMA, global_load_lds staging,
// XCD-bijective swizzle (256 wg/GEMM: each XCD owns one 128-col W panel).
//
// ws (<=89.5MB): ut f32[0,16) ra f16[16,24) ab f16[24,32) ei f16[32,40)
//  hup f16[40,48) inpH[48,56) hcH[56,64) WtH[64,68) TrH[68,70) WaH[70,74)
//  HwH[74,78) EhH[78,82) EiH[82,84) count[84MB] list[84MB+256, +5.2MB)
// out parking: hw -> out_h (overwritten by eh).

typedef __attribute__((ext_vector_type(4))) float f32x4;
typedef __attribute__((ext_vector_type(8))) _Float16 half8;
typedef __attribute__((ext_vector_type(4))) _Float16 half4;

#define NEL (4096 * 1024)
#define DELTA 0.02f
#define CAP 1300000

__device__ __forceinline__ float sigm(float x) { return 1.0f / (1.0f + expf(-x)); }

__device__ __forceinline__ void gload16(const void* g, void* l) {
  __builtin_amdgcn_global_load_lds(
      (const __attribute__((address_space(1))) void*)g,
      (__attribute__((address_space(3))) void*)l, 16, 0, 0);
}

// OP: 0 sigmoid->f32, 1 tanh->f32, 2 sigmoid->f16, 3 h_next epilogue->f32
template <int OP>
__device__ __forceinline__ void gemm_body(
    _Float16* sm, const int brow, const int bcol,
    const _Float16* A1h, const _Float16* A2h,
    const _Float16* Wh, const float* bias, const int K,
    float* outF, _Float16* outH, const float* hw_p, const float* hc_p)
{
  _Float16* As = sm;
  _Float16* Bs = sm + 4096;
  const int tid = threadIdx.x;
  const int lane = tid & 63;
  const int w = tid >> 6;
  const int wr = w >> 1, wc = w & 1;       // 2x2 waves, 64x64 each
  const int lr = lane & 15, lq = lane >> 4;
  const int r0 = tid >> 2;                 // staging row 0..63 (+64)
  const int cb = (tid & 3) * 8;            // 16B chunk (8 f16)

  f32x4 acc[4][4] = {};

  for (int k0 = 0; k0 < K; k0 += 32) {
    const _Float16* Ah = (k0 < 1024) ? A1h : A2h;
    const int kk = k0 & 1023;
    __syncthreads();
    gload16(Ah + (size_t)(brow + r0) * 1024 + kk + cb,      &As[r0 * 32 + cb]);
    gload16(Ah + (size_t)(brow + r0 + 64) * 1024 + kk + cb, &As[(r0 + 64) * 32 + cb]);
    gload16(Wh + (size_t)(bcol + r0) * K + k0 + cb,         &Bs[r0 * 32 + cb]);
    gload16(Wh + (size_t)(bcol + r0 + 64) * K + k0 + cb,    &Bs[(r0 + 64) * 32 + cb]);
    __syncthreads();

    half8 a[4], b[4];
#pragma unroll
    for (int m = 0; m < 4; ++m)
      a[m] = *(const half8*)&As[(wr * 64 + m * 16 + lr) * 32 + lq * 8];
#pragma unroll
    for (int n = 0; n < 4; ++n)
      b[n] = *(const half8*)&Bs[(wc * 64 + n * 16 + lr) * 32 + lq * 8];
#pragma unroll
    for (int m = 0; m < 4; ++m)
#pragma unroll
      for (int n = 0; n < 4; ++n)
        acc[m][n] = __builtin_amdgcn_mfma_f32_16x16x32_f16(a[m], b[n], acc[m][n], 0, 0, 0);
  }

  float bv[4];
#pragma unroll
  for (int n = 0; n < 4; ++n) bv[n] = bias[bcol + wc * 64 + n * 16 + lr];

#pragma unroll
  for (int m = 0; m < 4; ++m)
#pragma unroll
    for (int n = 0; n < 4; ++n) {
      const int col = bcol + wc * 64 + n * 16 + lr;
#pragma unroll
      for (int j = 0; j < 4; ++j) {
        const int rowg = brow + wr * 64 + m * 16 + lq * 4 + j;
        const size_t idx = (size_t)rowg * 1024 + col;
        const float v = acc[m][n][j] + bv[n];
        if (OP == 0)      outF[idx] = sigm(v);
        else if (OP == 1) outF[idx] = tanhf(v);
        else if (OP == 2) outH[idx] = (_Float16)sigm(v);
        else {
          const float hs = tanhf(v);
          const float hwv = hw_p[idx];
          const float hcv = hc_p[idx];
          outF[idx] = tanhf((1.0f - hwv) * hcv + hwv * hs);
        }
      }
    }
}

__device__ __forceinline__ void swz_block(int id, int& bx, int& by) {
  const int swz = (id & 7) * 32 + (id >> 3);  // bijective, XCD-chunked (nwg=256)
  bx = swz & 31;                              // row-block 0..31
  by = swz >> 5;                              // col-block 0..7 (one per XCD)
}

// z: 0=Wt(tanh->ut f32) 1=Wa(sig->ab f16) 2=Hw(sig->out_h f32)
//    3=Tr(sig->ra f16)  4=Ei(sig->ei f16)
__global__ __launch_bounds__(256, 3)
void qurnn_gemm5(const _Float16* inpH, const _Float16* hcH,
                 const _Float16* WtH, const float* Wt_b,
                 const _Float16* WaH, const float* Wa_b,
                 const _Float16* HwH, const float* Hw_b,
                 const _Float16* TrH, const float* Tr_b,
                 const _Float16* EiH, const float* Ei_b,
                 float* ws_ut, _Float16* ws_ab, float* out_h,
                 _Float16* ws_ra, _Float16* ws_ei)
{
  __shared__ __align__(16) _Float16 sm[2 * 4096];   // 16KB
  int bx, by; swz_block(blockIdx.x, bx, by);
  const int brow = bx * 128, bcol = by * 128;
  switch (blockIdx.z) {
    case 0: gemm_body<1>(sm, brow, bcol, inpH, hcH, WtH, Wt_b, 2048, ws_ut, nullptr, nullptr, nullptr); break;
    case 1: gemm_body<2>(sm, brow, bcol, inpH, hcH, WaH, Wa_b, 2048, nullptr, ws_ab, nullptr, nullptr); break;
    case 2: gemm_body<0>(sm, brow, bcol, inpH, hcH, HwH, Hw_b, 2048, out_h, nullptr, nullptr, nullptr); break;
    case 3: gemm_body<2>(sm, brow, bcol, inpH, nullptr, TrH, Tr_b, 1024, nullptr, ws_ra, nullptr, nullptr); break;
    default:gemm_body<2>(sm, brow, bcol, inpH, nullptr, EiH, Ei_b, 1024, nullptr, ws_ei, nullptr, nullptr); break;
  }
}

__global__ __launch_bounds__(256, 3)
void qurnn_eh(const _Float16* inpH, const _Float16* hup,
              const _Float16* EhH, const float* Eh_b,
              const float* hcur, float* out_h)
{
  __shared__ __align__(16) _Float16 sm[2 * 4096];
  int bx, by; swz_block(blockIdx.x, bx, by);
  gemm_body<3>(sm, bx * 128, by * 128, inpH, hup, EhH, Eh_b, 2048,
               out_h, nullptr, out_h, hcur);
}

__global__ __launch_bounds__(256)
void qurnn_cell(const f32x4* tc, const f32x4* ec, const f32x4* hc,
                const f32x4* ut, const half4* ra, const half4* ab,
                const half4* ei, f32x4* out_ex, f32x4* out_tm, half4* hup,
                int* count, int* list)
{
  const int i = blockIdx.x * 256 + threadIdx.x;   // exact: 4096 blocks
  const f32x4 tcv = tc[i], ecv = ec[i], hcv = hc[i], utv = ut[i];
  const half4 rav = ra[i], abv = ab[i], eiv = ei[i];
  f32x4 to, eo; half4 ho;
#pragma unroll
  for (int j = 0; j < 4; ++j) {
    const float t = (float)rav[j] * fmaxf(tcv[j] + utv[j], 0.0f) - 1.0f;
    const bool leap = (t <= 0.0f);
    to[j] = leap ? 0.0f : t;
    eo[j] = (leap ? 0.0f : ecv[j] + (float)eiv[j]) + (float)abv[j];
    ho[j] = (_Float16)(leap ? hcv[j] * ecv[j] : 0.0f);
    if (fabsf(t) < DELTA) {                 // leap decision uncertain -> flag
      const int pos = atomicAdd(count, 1);
      if (pos < CAP) list[pos] = i * 4 + j;
    }
  }
  out_tm[i] = to;
  out_ex[i] = eo;
  hup[i] = ho;
}

// Exact f32 recompute of ratio/ut for flagged elements; one wave per element.
__global__ __launch_bounds__(256)
void qurnn_fixup(const int* count, const int* list,
                 const float* inp, const float* hcur,
                 const float* Tr_w, const float* Tr_b,
                 const float* Wt_w, const float* Wt_b,
                 const _Float16* ei, const _Float16* ab,
                 const float* tc, const float* ec,
                 float* out_tm, float* out_ex, _Float16* hup)
{
  const int gtid = blockIdx.x * 256 + threadIdx.x;
  const int wid = gtid >> 6, lane = gtid & 63;
  const int nw = gridDim.x * 4;
  const int n = min(*count, CAP);
  for (int e = wid; e < n; e += nw) {
    const int idx = list[e];
    const int row = idx >> 10, col = idx & 1023;
    float dTr = 0.0f, dWt = 0.0f;
    const float* irow = inp + (size_t)row * 1024;
    const float* hrow = hcur + (size_t)row * 1024;
    const float* trw = Tr_w + (size_t)col * 1024;
    const float* wtw = Wt_w + (size_t)col * 2048;
    for (int k = lane; k < 1024; k += 64) {
      const float a = irow[k];
      dTr = fmaf(a, trw[k], dTr);
      dWt = fmaf(a, wtw[k], dWt);
      dWt = fmaf(hrow[k], wtw[1024 + k], dWt);
    }
#pragma unroll
    for (int s = 32; s; s >>= 1) {
      dTr += __shfl_down(dTr, s);
      dWt += __shfl_down(dWt, s);
    }
    if (lane == 0) {
      const float ratio = sigm(dTr + Tr_b[col]);
      const float utv = tanhf(dWt + Wt_b[col]);
      const float t = ratio * fmaxf(tc[idx] + utv, 0.0f) - 1.0f;
      const bool leap = (t <= 0.0f);
      out_tm[idx] = leap ? 0.0f : t;
      out_ex[idx] = (leap ? 0.0f : ec[idx] + (float)ei[idx]) + (float)ab[idx];
      hup[idx] = (_Float16)(leap ? hcur[idx] * ec[idx] : 0.0f);
    }
  }
}

// f32 -> f16 planes (hi only); z=0 also zeroes the fixup counter.
__global__ __launch_bounds__(256)
void convert_k(const float* inp, const float* hcur,
               const float* Wt_w, const float* Tr_w, const float* Wa_w,
               const float* Hw_w, const float* Eh_w, const float* Ei_w,
               _Float16* inpH, _Float16* hcH, _Float16* WtH, _Float16* TrH,
               _Float16* WaH, _Float16* HwH, _Float16* EhH, _Float16* EiH,
               int* count)
{
  if (blockIdx.z == 0 && blockIdx.x == 0 && threadIdx.x == 0) *count = 0;
  const float* src; _Float16* dh; int n4;
  switch (blockIdx.z) {
    case 0: src = inp;  dh = inpH; n4 = NEL / 4;           break;
    case 1: src = hcur; dh = hcH;  n4 = NEL / 4;           break;
    case 2: src = Wt_w; dh = WtH;  n4 = (1024 * 2048) / 4; break;
    case 3: src = Tr_w; dh = TrH;  n4 = (1024 * 1024) / 4; break;
    case 4: src = Wa_w; dh = WaH;  n4 = (1024 * 2048) / 4; break;
    case 5: src = Hw_w; dh = HwH;  n4 = (1024 * 2048) / 4; break;
    case 6: src = Eh_w; dh = EhH;  n4 = (1024 * 2048) / 4; break;
    default:src = Ei_w; dh = EiH;  n4 = (1024 * 1024) / 4; break;
  }
  for (int i = blockIdx.x * 256 + threadIdx.x; i < n4; i += gridDim.x * 256) {
    const f32x4 v = ((const f32x4*)src)[i];
    half4 h;
#pragma unroll
    for (int j = 0; j < 4; ++j) h[j] = (_Float16)v[j];
    ((half4*)dh)[i] = h;
  }
}

extern "C" void kernel_launch(void* const* d_in, const int* in_sizes, int n_in,
                              void* d_out, int out_size, void* d_ws, size_t ws_size,
                              hipStream_t stream)
{
  const float* inp  = (const float*)d_in[0];
  const float* hcur = (const float*)d_in[1];
  const float* ec   = (const float*)d_in[2];
  const float* tc   = (const float*)d_in[3];
  const float* Wt_w = (const float*)d_in[4];
  const float* Wt_b = (const float*)d_in[5];
  const float* Wa_w = (const float*)d_in[6];
  const float* Wa_b = (const float*)d_in[7];
  const float* Eh_w = (const float*)d_in[8];
  const float* Eh_b = (const float*)d_in[9];
  const float* Hw_w = (const float*)d_in[10];
  const float* Hw_b = (const float*)d_in[11];
  const float* Tr_w = (const float*)d_in[12];
  const float* Tr_b = (const float*)d_in[13];
  const float* Ei_w = (const float*)d_in[14];
  const float* Ei_b = (const float*)d_in[15];

  float* out_h  = (float*)d_out;
  float* out_ex = out_h + NEL;
  float* out_tm = out_ex + NEL;

  char* wsb = (char*)d_ws;
  float*    ws_ut  = (float*)(wsb);
  _Float16* ws_ra  = (_Float16*)(wsb + (16u << 20));
  _Float16* ws_ab  = (_Float16*)(wsb + (24u << 20));
  _Float16* ws_ei  = (_Float16*)(wsb + (32u << 20));
  _Float16* ws_hup = (_Float16*)(wsb + (40u << 20));
  _Float16* inpH   = (_Float16*)(wsb + (48u << 20));
  _Float16* hcH    = (_Float16*)(wsb + (56u << 20));
  _Float16* WtH    = (_Float16*)(wsb + (64u << 20));
  _Float16* TrH    = (_Float16*)(wsb + (68u << 20));
  _Float16* WaH    = (_Float16*)(wsb + (70u << 20));
  _Float16* HwH    = (_Float16*)(wsb + (74u << 20));
  _Float16* EhH    = (_Float16*)(wsb + (78u << 20));
  _Float16* EiH    = (_Float16*)(wsb + (82u << 20));
  int*      d_cnt  = (int*)(wsb + (84u << 20));
  int*      d_list = (int*)(wsb + (84u << 20) + 256);

  // Phase 0: f32 -> f16 planes (+ counter reset)
  convert_k<<<dim3(512, 1, 8), 256, 0, stream>>>(
      inp, hcur, Wt_w, Tr_w, Wa_w, Hw_w, Eh_w, Ei_w,
      inpH, hcH, WtH, TrH, WaH, HwH, EhH, EiH, d_cnt);

  // Phase 1: 5 GEMMs (heavy K=2048 first)
  qurnn_gemm5<<<dim3(256, 1, 5), 256, 0, stream>>>(
      inpH, hcH, WtH, Wt_b, WaH, Wa_b, HwH, Hw_b, TrH, Tr_b, EiH, Ei_b,
      ws_ut, ws_ab, out_h, ws_ra, ws_ei);

  // Phase 2: elementwise cell update + boundary flagging
  qurnn_cell<<<dim3(4096), 256, 0, stream>>>(
      (const f32x4*)tc, (const f32x4*)ec, (const f32x4*)hcur,
      (const f32x4*)ws_ut, (const half4*)ws_ra, (const half4*)ws_ab,
      (const half4*)ws_ei, (f32x4*)out_ex, (f32x4*)out_tm, (half4*)ws_hup,
      d_cnt, d_list);

  // Phase 3: exact recompute for leap-boundary elements
  qurnn_fixup<<<dim3(512), 256, 0, stream>>>(
      d_cnt, d_list, inp, hcur, Tr_w, Tr_b, Wt_w, Wt_b,
      ws_ei, ws_ab, tc, ec, out_tm, out_ex, ws_hup);

  // Phase 4: Eh GEMM on [inp | h_up] + fused h_next epilogue
  qurnn_eh<<<dim3(256), 256, 0, stream>>>(inpH, ws_hup, EhH, Eh_b, hcur, out_h);
}

// Round 5
// 244.632 us; speedup vs baseline: 2.2284x; 2.2284x over previous
//
#include <hip/hip_runtime.h>
#include <math.h>

// QURNN cell, MI355X gfx950, f32 I/O. B=4096, D_IN=D_H=1024.
//
// Round 5: same single-f16 GEMM + boundary-fixup scheme as round 4, with the
// atomic-contention disaster fixed:
//  - cell: LDS-aggregated compaction (one global atomicAdd per BLOCK, not per
//    element; round 4's per-element same-address far atomics serialized at
//    ~300-600cyc across XCDs -> 265us).
//  - DELTA 0.02 -> 6e-3 (~12 sigma of f16-GEMM + f16-storage error on t).
//  - fixup: f32x4 coalesced row reads (1KB/instr per wave).
//  - ut stored f16 (error covered by DELTA; fixup recomputes exactly).
//
// Dispatches: convert -> gemm5 (Wt,Wa,Hw,Tr,Ei) -> cell -> fixup -> eh
// GEMM: 128x128 tile, BK=32, 16x16x32 f16 MFMA, global_load_lds staging,
// XCD-bijective swizzle (256 wg/GEMM: each XCD owns one 128-col W panel).
//
// ws (<=82MB): ut f16[0,8M) ra[8,16) ab[16,24) ei[24,32) hup[32,40)
//  inpH[40,48) hcH[48,56) WtH[56,60) TrH[60,62) WaH[62,66) HwH[66,70)
//  EhH[70,74) EiH[74,76) cnt@76M list@76M+256 (cap 1.3M idx)
// out parking: hw -> out_h (overwritten by eh).

typedef __attribute__((ext_vector_type(4))) float f32x4;
typedef __attribute__((ext_vector_type(8))) _Float16 half8;
typedef __attribute__((ext_vector_type(4))) _Float16 half4;

#define NEL (4096 * 1024)
#define DELTA 6.0e-3f
#define CAP 1300000

__device__ __forceinline__ float sigm(float x) { return 1.0f / (1.0f + expf(-x)); }

__device__ __forceinline__ void gload16(const void* g, void* l) {
  __builtin_amdgcn_global_load_lds(
      (const __attribute__((address_space(1))) void*)g,
      (__attribute__((address_space(3))) void*)l, 16, 0, 0);
}

// OP: 0 sigmoid->f32, 1 tanh->f16, 2 sigmoid->f16, 3 h_next epilogue->f32
template <int OP>
__device__ __forceinline__ void gemm_body(
    _Float16* sm, const int brow, const int bcol,
    const _Float16* A1h, const _Float16* A2h,
    const _Float16* Wh, const float* bias, const int K,
    float* outF, _Float16* outH, const float* hw_p, const float* hc_p)
{
  _Float16* As = sm;
  _Float16* Bs = sm + 4096;
  const int tid = threadIdx.x;
  const int lane = tid & 63;
  const int w = tid >> 6;
  const int wr = w >> 1, wc = w & 1;       // 2x2 waves, 64x64 each
  const int lr = lane & 15, lq = lane >> 4;
  const int r0 = tid >> 2;                 // staging row 0..63 (+64)
  const int cb = (tid & 3) * 8;            // 16B chunk (8 f16)

  f32x4 acc[4][4] = {};

  for (int k0 = 0; k0 < K; k0 += 32) {
    const _Float16* Ah = (k0 < 1024) ? A1h : A2h;
    const int kk = k0 & 1023;
    __syncthreads();
    gload16(Ah + (size_t)(brow + r0) * 1024 + kk + cb,      &As[r0 * 32 + cb]);
    gload16(Ah + (size_t)(brow + r0 + 64) * 1024 + kk + cb, &As[(r0 + 64) * 32 + cb]);
    gload16(Wh + (size_t)(bcol + r0) * K + k0 + cb,         &Bs[r0 * 32 + cb]);
    gload16(Wh + (size_t)(bcol + r0 + 64) * K + k0 + cb,    &Bs[(r0 + 64) * 32 + cb]);
    __syncthreads();

    half8 a[4], b[4];
#pragma unroll
    for (int m = 0; m < 4; ++m)
      a[m] = *(const half8*)&As[(wr * 64 + m * 16 + lr) * 32 + lq * 8];
#pragma unroll
    for (int n = 0; n < 4; ++n)
      b[n] = *(const half8*)&Bs[(wc * 64 + n * 16 + lr) * 32 + lq * 8];
#pragma unroll
    for (int m = 0; m < 4; ++m)
#pragma unroll
      for (int n = 0; n < 4; ++n)
        acc[m][n] = __builtin_amdgcn_mfma_f32_16x16x32_f16(a[m], b[n], acc[m][n], 0, 0, 0);
  }

  float bv[4];
#pragma unroll
  for (int n = 0; n < 4; ++n) bv[n] = bias[bcol + wc * 64 + n * 16 + lr];

#pragma unroll
  for (int m = 0; m < 4; ++m)
#pragma unroll
    for (int n = 0; n < 4; ++n) {
      const int col = bcol + wc * 64 + n * 16 + lr;
#pragma unroll
      for (int j = 0; j < 4; ++j) {
        const int rowg = brow + wr * 64 + m * 16 + lq * 4 + j;
        const size_t idx = (size_t)rowg * 1024 + col;
        const float v = acc[m][n][j] + bv[n];
        if (OP == 0)      outF[idx] = sigm(v);
        else if (OP == 1) outH[idx] = (_Float16)tanhf(v);
        else if (OP == 2) outH[idx] = (_Float16)sigm(v);
        else {
          const float hs = tanhf(v);
          const float hwv = hw_p[idx];
          const float hcv = hc_p[idx];
          outF[idx] = tanhf((1.0f - hwv) * hcv + hwv * hs);
        }
      }
    }
}

__device__ __forceinline__ void swz_block(int id, int& bx, int& by) {
  const int swz = (id & 7) * 32 + (id >> 3);  // bijective, XCD-chunked (nwg=256)
  bx = swz & 31;
  by = swz >> 5;
}

// z: 0=Wt(tanh->ut f16) 1=Wa(sig->ab f16) 2=Hw(sig->out_h f32)
//    3=Tr(sig->ra f16)  4=Ei(sig->ei f16)
__global__ __launch_bounds__(256, 3)
void qurnn_gemm5(const _Float16* inpH, const _Float16* hcH,
                 const _Float16* WtH, const float* Wt_b,
                 const _Float16* WaH, const float* Wa_b,
                 const _Float16* HwH, const float* Hw_b,
                 const _Float16* TrH, const float* Tr_b,
                 const _Float16* EiH, const float* Ei_b,
                 _Float16* ws_ut, _Float16* ws_ab, float* out_h,
                 _Float16* ws_ra, _Float16* ws_ei)
{
  __shared__ __align__(16) _Float16 sm[2 * 4096];   // 16KB
  int bx, by; swz_block(blockIdx.x, bx, by);
  const int brow = bx * 128, bcol = by * 128;
  switch (blockIdx.z) {
    case 0: gemm_body<1>(sm, brow, bcol, inpH, hcH, WtH, Wt_b, 2048, nullptr, ws_ut, nullptr, nullptr); break;
    case 1: gemm_body<2>(sm, brow, bcol, inpH, hcH, WaH, Wa_b, 2048, nullptr, ws_ab, nullptr, nullptr); break;
    case 2: gemm_body<0>(sm, brow, bcol, inpH, hcH, HwH, Hw_b, 2048, out_h, nullptr, nullptr, nullptr); break;
    case 3: gemm_body<2>(sm, brow, bcol, inpH, nullptr, TrH, Tr_b, 1024, nullptr, ws_ra, nullptr, nullptr); break;
    default:gemm_body<2>(sm, brow, bcol, inpH, nullptr, EiH, Ei_b, 1024, nullptr, ws_ei, nullptr, nullptr); break;
  }
}

__global__ __launch_bounds__(256, 3)
void qurnn_eh(const _Float16* inpH, const _Float16* hup,
              const _Float16* EhH, const float* Eh_b,
              const float* hcur, float* out_h)
{
  __shared__ __align__(16) _Float16 sm[2 * 4096];
  int bx, by; swz_block(blockIdx.x, bx, by);
  gemm_body<3>(sm, bx * 128, by * 128, inpH, hup, EhH, Eh_b, 2048,
               out_h, nullptr, out_h, hcur);
}

__global__ __launch_bounds__(256)
void qurnn_cell(const f32x4* tc, const f32x4* ec, const f32x4* hc,
                const half4* ut, const half4* ra, const half4* ab,
                const half4* ei, f32x4* out_ex, f32x4* out_tm, half4* hup,
                int* count, int* list)
{
  __shared__ int l_cnt, l_base;
  __shared__ int l_idx[1024];               // max 4 flags/thread * 256
  if (threadIdx.x == 0) l_cnt = 0;
  __syncthreads();

  const int i = blockIdx.x * 256 + threadIdx.x;   // exact: 4096 blocks
  const f32x4 tcv = tc[i], ecv = ec[i], hcv = hc[i];
  const half4 utv = ut[i], rav = ra[i], abv = ab[i], eiv = ei[i];
  f32x4 to, eo; half4 ho;
#pragma unroll
  for (int j = 0; j < 4; ++j) {
    const float t = (float)rav[j] * fmaxf(tcv[j] + (float)utv[j], 0.0f) - 1.0f;
    const bool leap = (t <= 0.0f);
    to[j] = leap ? 0.0f : t;
    eo[j] = (leap ? 0.0f : ecv[j] + (float)eiv[j]) + (float)abv[j];
    ho[j] = (_Float16)(leap ? hcv[j] * ecv[j] : 0.0f);
    if (fabsf(t) < DELTA) {                 // leap uncertain -> LDS-compact
      const int p = atomicAdd(&l_cnt, 1);
      l_idx[p] = i * 4 + j;
    }
  }
  out_tm[i] = to;
  out_ex[i] = eo;
  hup[i] = ho;

  __syncthreads();
  if (threadIdx.x == 0 && l_cnt > 0) l_base = atomicAdd(count, l_cnt);
  __syncthreads();
  for (int e = threadIdx.x; e < l_cnt; e += 256) {
    const int pos = l_base + e;
    if (pos < CAP) list[pos] = l_idx[e];
  }
}

// Exact f32 recompute of ratio/ut for flagged elements; one wave per element.
__global__ __launch_bounds__(256)
void qurnn_fixup(const int* count, const int* list,
                 const float* inp, const float* hcur,
                 const float* Tr_w, const float* Tr_b,
                 const float* Wt_w, const float* Wt_b,
                 const _Float16* ei, const _Float16* ab,
                 const float* tc, const float* ec,
                 float* out_tm, float* out_ex, _Float16* hup)
{
  const int gtid = blockIdx.x * 256 + threadIdx.x;
  const int wid = gtid >> 6, lane = gtid & 63;
  const int nw = gridDim.x * 4;
  const int n = min(*count, CAP);
  for (int e = wid; e < n; e += nw) {
    const int idx = list[e];
    const int row = idx >> 10, col = idx & 1023;
    const f32x4* irow = (const f32x4*)(inp  + (size_t)row * 1024);
    const f32x4* hrow = (const f32x4*)(hcur + (size_t)row * 1024);
    const f32x4* trw  = (const f32x4*)(Tr_w + (size_t)col * 1024);
    const f32x4* wtw  = (const f32x4*)(Wt_w + (size_t)col * 2048);
    float dTr = 0.0f, dWt = 0.0f;
#pragma unroll
    for (int k = 0; k < 4; ++k) {           // 256 f32x4 per row / 64 lanes
      const int q = k * 64 + lane;
      const f32x4 a = irow[q], h = hrow[q];
      const f32x4 w1 = trw[q], w2 = wtw[q], w3 = wtw[256 + q];
#pragma unroll
      for (int j = 0; j < 4; ++j) {
        dTr = fmaf(a[j], w1[j], dTr);
        dWt = fmaf(a[j], w2[j], dWt);
        dWt = fmaf(h[j], w3[j], dWt);
      }
    }
#pragma unroll
    for (int s = 32; s; s >>= 1) {
      dTr += __shfl_xor(dTr, s);
      dWt += __shfl_xor(dWt, s);
    }
    if (lane == 0) {
      const float ratio = sigm(dTr + Tr_b[col]);
      const float utv = tanhf(dWt + Wt_b[col]);
      const float t = ratio * fmaxf(tc[idx] + utv, 0.0f) - 1.0f;
      const bool leap = (t <= 0.0f);
      out_tm[idx] = leap ? 0.0f : t;
      out_ex[idx] = (leap ? 0.0f : ec[idx] + (float)ei[idx]) + (float)ab[idx];
      hup[idx] = (_Float16)(leap ? hcur[idx] * ec[idx] : 0.0f);
    }
  }
}

// f32 -> f16 planes (hi only); z=0 also zeroes the fixup counter.
__global__ __launch_bounds__(256)
void convert_k(const float* inp, const float* hcur,
               const float* Wt_w, const float* Tr_w, const float* Wa_w,
               const float* Hw_w, const float* Eh_w, const float* Ei_w,
               _Float16* inpH, _Float16* hcH, _Float16* WtH, _Float16* TrH,
               _Float16* WaH, _Float16* HwH, _Float16* EhH, _Float16* EiH,
               int* count)
{
  if (blockIdx.z == 0 && blockIdx.x == 0 && threadIdx.x == 0) *count = 0;
  const float* src; _Float16* dh; int n4;
  switch (blockIdx.z) {
    case 0: src = inp;  dh = inpH; n4 = NEL / 4;           break;
    case 1: src = hcur; dh = hcH;  n4 = NEL / 4;           break;
    case 2: src = Wt_w; dh = WtH;  n4 = (1024 * 2048) / 4; break;
    case 3: src = Tr_w; dh = TrH;  n4 = (1024 * 1024) / 4; break;
    case 4: src = Wa_w; dh = WaH;  n4 = (1024 * 2048) / 4; break;
    case 5: src = Hw_w; dh = HwH;  n4 = (1024 * 2048) / 4; break;
    case 6: src = Eh_w; dh = EhH;  n4 = (1024 * 2048) / 4; break;
    default:src = Ei_w; dh = EiH;  n4 = (1024 * 1024) / 4; break;
  }
  for (int i = blockIdx.x * 256 + threadIdx.x; i < n4; i += gridDim.x * 256) {
    const f32x4 v = ((const f32x4*)src)[i];
    half4 h;
#pragma unroll
    for (int j = 0; j < 4; ++j) h[j] = (_Float16)v[j];
    ((half4*)dh)[i] = h;
  }
}

extern "C" void kernel_launch(void* const* d_in, const int* in_sizes, int n_in,
                              void* d_out, int out_size, void* d_ws, size_t ws_size,
                              hipStream_t stream)
{
  const float* inp  = (const float*)d_in[0];
  const float* hcur = (const float*)d_in[1];
  const float* ec   = (const float*)d_in[2];
  const float* tc   = (const float*)d_in[3];
  const float* Wt_w = (const float*)d_in[4];
  const float* Wt_b = (const float*)d_in[5];
  const float* Wa_w = (const float*)d_in[6];
  const float* Wa_b = (const float*)d_in[7];
  const float* Eh_w = (const float*)d_in[8];
  const float* Eh_b = (const float*)d_in[9];
  const float* Hw_w = (const float*)d_in[10];
  const float* Hw_b = (const float*)d_in[11];
  const float* Tr_w = (const float*)d_in[12];
  const float* Tr_b = (const float*)d_in[13];
  const float* Ei_w = (const float*)d_in[14];
  const float* Ei_b = (const float*)d_in[15];

  float* out_h  = (float*)d_out;
  float* out_ex = out_h + NEL;
  float* out_tm = out_ex + NEL;

  char* wsb = (char*)d_ws;
  _Float16* ws_ut  = (_Float16*)(wsb);
  _Float16* ws_ra  = (_Float16*)(wsb + (8u  << 20));
  _Float16* ws_ab  = (_Float16*)(wsb + (16u << 20));
  _Float16* ws_ei  = (_Float16*)(wsb + (24u << 20));
  _Float16* ws_hup = (_Float16*)(wsb + (32u << 20));
  _Float16* inpH   = (_Float16*)(wsb + (40u << 20));
  _Float16* hcH    = (_Float16*)(wsb + (48u << 20));
  _Float16* WtH    = (_Float16*)(wsb + (56u << 20));
  _Float16* TrH    = (_Float16*)(wsb + (60u << 20));
  _Float16* WaH    = (_Float16*)(wsb + (62u << 20));
  _Float16* HwH    = (_Float16*)(wsb + (66u << 20));
  _Float16* EhH    = (_Float16*)(wsb + (70u << 20));
  _Float16* EiH    = (_Float16*)(wsb + (74u << 20));
  int*      d_cnt  = (int*)(wsb + (76u << 20));
  int*      d_list = (int*)(wsb + (76u << 20) + 256);

  // Phase 0: f32 -> f16 planes (+ counter reset)
  convert_k<<<dim3(512, 1, 8), 256, 0, stream>>>(
      inp, hcur, Wt_w, Tr_w, Wa_w, Hw_w, Eh_w, Ei_w,
      inpH, hcH, WtH, TrH, WaH, HwH, EhH, EiH, d_cnt);

  // Phase 1: 5 GEMMs (heavy K=2048 first)
  qurnn_gemm5<<<dim3(256, 1, 5), 256, 0, stream>>>(
      inpH, hcH, WtH, Wt_b, WaH, Wa_b, HwH, Hw_b, TrH, Tr_b, EiH, Ei_b,
      ws_ut, ws_ab, out_h, ws_ra, ws_ei);

  // Phase 2: elementwise cell update + LDS-compacted boundary flagging
  qurnn_cell<<<dim3(4096), 256, 0, stream>>>(
      (const f32x4*)tc, (const f32x4*)ec, (const f32x4*)hcur,
      (const half4*)ws_ut, (const half4*)ws_ra, (const half4*)ws_ab,
      (const half4*)ws_ei, (f32x4*)out_ex, (f32x4*)out_tm, (half4*)ws_hup,
      d_cnt, d_list);

  // Phase 3: exact recompute for leap-boundary elements
  qurnn_fixup<<<dim3(1024), 256, 0, stream>>>(
      d_cnt, d_list, inp, hcur, Tr_w, Tr_b, Wt_w, Wt_b,
      ws_ei, ws_ab, tc, ec, out_tm, out_ex, ws_hup);

  // Phase 4: Eh GEMM on [inp | h_up] + fused h_next epilogue
  qurnn_eh<<<dim3(256), 256, 0, stream>>>(inpH, ws_hup, EhH, Eh_b, hcur, out_h);
}

// Round 6
// 210.573 us; speedup vs baseline: 2.5888x; 1.1617x over previous
//
#include <hip/hip_runtime.h>
#include <math.h>

// QURNN cell, MI355X gfx950, f32 I/O. B=4096, D_IN=D_H=1024.
//
// Round 6: single-f16 GEMMs + leap-boundary fixup (round-5 scheme) with:
//  - BK=64 tiles (128B f16 rows) + involution chunk-swizzle: source-side
//    pre-swizzle (global addr) + same XOR on ds_read; LDS linear so
//    global_load_lds works. Read banks: ((chunk)^(row&7))*4 -> 2-way (free).
//  - no XCD swizzle (all operands L3-resident; swizzle is -2% when L3-fit).
//  - ra/ut kept f32 (no f16 storage error) -> DELTA 3e-3, half the fixup.
//  - h_weight f16 in ws (cuts 16MB f32 traffic).
//
// Dispatches: convert -> gemm5 (Wt,Wa,Hw,Tr,Ei) -> cell -> fixup -> eh
//
// ws (<=90MB): ut f32[0,16) ab f16[16,24) ei f16[24,32) hup f16[32,40)
//  hw f16[40,48) inpH[48,56) hcH[56,64) WtH[64,68) TrH[68,70) WaH[70,74)
//  HwH[74,78) EhH[78,82) EiH[82,84) cnt@84M list@84M+256
// out parking: ratio f32 -> out_tm region (cell reads then overwrites).

typedef __attribute__((ext_vector_type(4))) float f32x4;
typedef __attribute__((ext_vector_type(8))) _Float16 half8;
typedef __attribute__((ext_vector_type(4))) _Float16 half4;

#define NEL (4096 * 1024)
#define DELTA 3.0e-3f
#define CAP 1300000

__device__ __forceinline__ float sigm(float x) { return 1.0f / (1.0f + expf(-x)); }

__device__ __forceinline__ void gload16(const void* g, void* l) {
  __builtin_amdgcn_global_load_lds(
      (const __attribute__((address_space(1))) void*)g,
      (__attribute__((address_space(3))) void*)l, 16, 0, 0);
}

// OP: 0 sigmoid->f32, 1 tanh->f32, 2 sigmoid->f16, 3 h_next epilogue->f32
template <int OP>
__device__ __forceinline__ void gemm_body(
    _Float16* sm, const int brow, const int bcol,
    const _Float16* A1h, const _Float16* A2h,
    const _Float16* Wh, const float* bias, const int K,
    float* outF, _Float16* outH, const _Float16* hw_p, const float* hc_p)
{
  _Float16* As = sm;            // [128][64] f16, 16KB
  _Float16* Bs = sm + 8192;     // [128][64] f16, 16KB
  const int tid = threadIdx.x;
  const int lane = tid & 63;
  const int w = tid >> 6;
  const int wr = w >> 1, wc = w & 1;       // 2x2 waves, 64x64 each
  const int lr = lane & 15, lq = lane >> 4;

  f32x4 acc[4][4] = {};

  for (int k0 = 0; k0 < K; k0 += 64) {
    const _Float16* Ah = (k0 < 1024) ? A1h : A2h;
    const int kk = k0 & 1023;
    __syncthreads();
#pragma unroll
    for (int i = 0; i < 4; ++i) {
      const int c_lin = i * 256 + tid;      // 1024 chunks of 16B per tile
      const int row = c_lin >> 3;           // 0..127
      const int c = c_lin & 7;              // linear LDS chunk
      const int src = (c ^ (row & 7)) * 8;  // involution: swizzled source
      gload16(Ah + (size_t)(brow + row) * 1024 + kk + src, &As[row * 64 + c * 8]);
      gload16(Wh + (size_t)(bcol + row) * K + k0 + src,    &Bs[row * 64 + c * 8]);
    }
    __syncthreads();

#pragma unroll
    for (int h = 0; h < 2; ++h) {
      half8 a[4], b[4];
#pragma unroll
      for (int m = 0; m < 4; ++m) {
        const int row = wr * 64 + m * 16 + lr;
        const int ch = (lq + 4 * h) ^ (row & 7);   // same involution on read
        a[m] = *(const half8*)&As[row * 64 + ch * 8];
      }
#pragma unroll
      for (int n = 0; n < 4; ++n) {
        const int row = wc * 64 + n * 16 + lr;
        const int ch = (lq + 4 * h) ^ (row & 7);
        b[n] = *(const half8*)&Bs[row * 64 + ch * 8];
      }
#pragma unroll
      for (int m = 0; m < 4; ++m)
#pragma unroll
        for (int n = 0; n < 4; ++n)
          acc[m][n] = __builtin_amdgcn_mfma_f32_16x16x32_f16(a[m], b[n], acc[m][n], 0, 0, 0);
    }
  }

  float bv[4];
#pragma unroll
  for (int n = 0; n < 4; ++n) bv[n] = bias[bcol + wc * 64 + n * 16 + lr];

#pragma unroll
  for (int m = 0; m < 4; ++m)
#pragma unroll
    for (int n = 0; n < 4; ++n) {
      const int col = bcol + wc * 64 + n * 16 + lr;
#pragma unroll
      for (int j = 0; j < 4; ++j) {
        const int rowg = brow + wr * 64 + m * 16 + lq * 4 + j;
        const size_t idx = (size_t)rowg * 1024 + col;
        const float v = acc[m][n][j] + bv[n];
        if (OP == 0)      outF[idx] = sigm(v);
        else if (OP == 1) outF[idx] = tanhf(v);
        else if (OP == 2) outH[idx] = (_Float16)sigm(v);
        else {
          const float hs = tanhf(v);
          const float hwv = (float)hw_p[idx];
          const float hcv = hc_p[idx];
          outF[idx] = tanhf((1.0f - hwv) * hcv + hwv * hs);
        }
      }
    }
}

// z: 0=Wt(tanh->ut f32) 1=Wa(sig->ab f16) 2=Hw(sig->hw f16)
//    3=Tr(sig->ratio f32, parked in out_tm) 4=Ei(sig->ei f16)
__global__ __launch_bounds__(256, 3)
void qurnn_gemm5(const _Float16* inpH, const _Float16* hcH,
                 const _Float16* WtH, const float* Wt_b,
                 const _Float16* WaH, const float* Wa_b,
                 const _Float16* HwH, const float* Hw_b,
                 const _Float16* TrH, const float* Tr_b,
                 const _Float16* EiH, const float* Ei_b,
                 float* ws_ut, _Float16* ws_ab, _Float16* ws_hw,
                 float* out_tm, _Float16* ws_ei)
{
  __shared__ __align__(16) _Float16 sm[2 * 8192];   // 32KB
  const int brow = (blockIdx.x & 31) * 128;         // x-fastest: same col panel
  const int bcol = (blockIdx.x >> 5) * 128;
  switch (blockIdx.z) {
    case 0: gemm_body<1>(sm, brow, bcol, inpH, hcH, WtH, Wt_b, 2048, ws_ut, nullptr, nullptr, nullptr); break;
    case 1: gemm_body<2>(sm, brow, bcol, inpH, hcH, WaH, Wa_b, 2048, nullptr, ws_ab, nullptr, nullptr); break;
    case 2: gemm_body<2>(sm, brow, bcol, inpH, hcH, HwH, Hw_b, 2048, nullptr, ws_hw, nullptr, nullptr); break;
    case 3: gemm_body<0>(sm, brow, bcol, inpH, nullptr, TrH, Tr_b, 1024, out_tm, nullptr, nullptr, nullptr); break;
    default:gemm_body<2>(sm, brow, bcol, inpH, nullptr, EiH, Ei_b, 1024, nullptr, ws_ei, nullptr, nullptr); break;
  }
}

__global__ __launch_bounds__(256, 3)
void qurnn_eh(const _Float16* inpH, const _Float16* hup,
              const _Float16* EhH, const float* Eh_b,
              const _Float16* hw, const float* hcur, float* out_h)
{
  __shared__ __align__(16) _Float16 sm[2 * 8192];
  const int brow = (blockIdx.x & 31) * 128;
  const int bcol = (blockIdx.x >> 5) * 128;
  gemm_body<3>(sm, brow, bcol, inpH, hup, EhH, Eh_b, 2048,
               out_h, nullptr, hw, hcur);
}

__global__ __launch_bounds__(256)
void qurnn_cell(const f32x4* tc, const f32x4* ec, const f32x4* hc,
                const f32x4* ut, const half4* ab, const half4* ei,
                f32x4* out_ex, f32x4* out_tm, half4* hup,
                int* count, int* list)
{
  __shared__ int l_cnt, l_base;
  __shared__ int l_idx[1024];
  if (threadIdx.x == 0) l_cnt = 0;
  __syncthreads();

  const int i = blockIdx.x * 256 + threadIdx.x;   // exact: 4096 blocks
  const f32x4 tcv = tc[i], ecv = ec[i], hcv = hc[i];
  const f32x4 rav = out_tm[i];    // ratio parked in time-out region (f32)
  const f32x4 utv = ut[i];
  const half4 abv = ab[i], eiv = ei[i];
  f32x4 to, eo; half4 ho;
#pragma unroll
  for (int j = 0; j < 4; ++j) {
    const float t = rav[j] * fmaxf(tcv[j] + utv[j], 0.0f) - 1.0f;
    const bool leap = (t <= 0.0f);
    to[j] = leap ? 0.0f : t;
    eo[j] = (leap ? 0.0f : ecv[j] + (float)eiv[j]) + (float)abv[j];
    ho[j] = (_Float16)(leap ? hcv[j] * ecv[j] : 0.0f);
    if (fabsf(t) < DELTA) {
      const int p = atomicAdd(&l_cnt, 1);
      l_idx[p] = i * 4 + j;
    }
  }
  out_tm[i] = to;
  out_ex[i] = eo;
  hup[i] = ho;

  __syncthreads();
  if (threadIdx.x == 0 && l_cnt > 0) l_base = atomicAdd(count, l_cnt);
  __syncthreads();
  for (int e = threadIdx.x; e < l_cnt; e += 256) {
    const int pos = l_base + e;
    if (pos < CAP) list[pos] = l_idx[e];
  }
}

// Exact f32 recompute of ratio/ut for flagged elements; one wave per element.
__global__ __launch_bounds__(256)
void qurnn_fixup(const int* count, const int* list,
                 const float* inp, const float* hcur,
                 const float* Tr_w, const float* Tr_b,
                 const float* Wt_w, const float* Wt_b,
                 const _Float16* ei, const _Float16* ab,
                 const float* tc, const float* ec,
                 float* out_tm, float* out_ex, _Float16* hup)
{
  const int gtid = blockIdx.x * 256 + threadIdx.x;
  const int wid = gtid >> 6, lane = gtid & 63;
  const int nw = gridDim.x * 4;
  const int n = min(*count, CAP);
  for (int e = wid; e < n; e += nw) {
    const int idx = list[e];
    const int row = idx >> 10, col = idx & 1023;
    const f32x4* irow = (const f32x4*)(inp  + (size_t)row * 1024);
    const f32x4* hrow = (const f32x4*)(hcur + (size_t)row * 1024);
    const f32x4* trw  = (const f32x4*)(Tr_w + (size_t)col * 1024);
    const f32x4* wtw  = (const f32x4*)(Wt_w + (size_t)col * 2048);
    float dTr = 0.0f, dWt = 0.0f;
#pragma unroll
    for (int k = 0; k < 4; ++k) {
      const int q = k * 64 + lane;
      const f32x4 a = irow[q], h = hrow[q];
      const f32x4 w1 = trw[q], w2 = wtw[q], w3 = wtw[256 + q];
#pragma unroll
      for (int j = 0; j < 4; ++j) {
        dTr = fmaf(a[j], w1[j], dTr);
        dWt = fmaf(a[j], w2[j], dWt);
        dWt = fmaf(h[j], w3[j], dWt);
      }
    }
#pragma unroll
    for (int s = 32; s; s >>= 1) {
      dTr += __shfl_xor(dTr, s);
      dWt += __shfl_xor(dWt, s);
    }
    if (lane == 0) {
      const float ratio = sigm(dTr + Tr_b[col]);
      const float utv = tanhf(dWt + Wt_b[col]);
      const float t = ratio * fmaxf(tc[idx] + utv, 0.0f) - 1.0f;
      const bool leap = (t <= 0.0f);
      out_tm[idx] = leap ? 0.0f : t;
      out_ex[idx] = (leap ? 0.0f : ec[idx] + (float)ei[idx]) + (float)ab[idx];
      hup[idx] = (_Float16)(leap ? hcur[idx] * ec[idx] : 0.0f);
    }
  }
}

// f32 -> f16 planes; z=0 also zeroes the fixup counter.
__global__ __launch_bounds__(256)
void convert_k(const float* inp, const float* hcur,
               const float* Wt_w, const float* Tr_w, const float* Wa_w,
               const float* Hw_w, const float* Eh_w, const float* Ei_w,
               _Float16* inpH, _Float16* hcH, _Float16* WtH, _Float16* TrH,
               _Float16* WaH, _Float16* HwH, _Float16* EhH, _Float16* EiH,
               int* count)
{
  if (blockIdx.z == 0 && blockIdx.x == 0 && threadIdx.x == 0) *count = 0;
  const float* src; _Float16* dh; int n4;
  switch (blockIdx.z) {
    case 0: src = inp;  dh = inpH; n4 = NEL / 4;           break;
    case 1: src = hcur; dh = hcH;  n4 = NEL / 4;           break;
    case 2: src = Wt_w; dh = WtH;  n4 = (1024 * 2048) / 4; break;
    case 3: src = Tr_w; dh = TrH;  n4 = (1024 * 1024) / 4; break;
    case 4: src = Wa_w; dh = WaH;  n4 = (1024 * 2048) / 4; break;
    case 5: src = Hw_w; dh = HwH;  n4 = (1024 * 2048) / 4; break;
    case 6: src = Eh_w; dh = EhH;  n4 = (1024 * 2048) / 4; break;
    default:src = Ei_w; dh = EiH;  n4 = (1024 * 1024) / 4; break;
  }
  for (int i = blockIdx.x * 256 + threadIdx.x; i < n4; i += gridDim.x * 256) {
    const f32x4 v = ((const f32x4*)src)[i];
    half4 h;
#pragma unroll
    for (int j = 0; j < 4; ++j) h[j] = (_Float16)v[j];
    ((half4*)dh)[i] = h;
  }
}

extern "C" void kernel_launch(void* const* d_in, const int* in_sizes, int n_in,
                              void* d_out, int out_size, void* d_ws, size_t ws_size,
                              hipStream_t stream)
{
  const float* inp  = (const float*)d_in[0];
  const float* hcur = (const float*)d_in[1];
  const float* ec   = (const float*)d_in[2];
  const float* tc   = (const float*)d_in[3];
  const float* Wt_w = (const float*)d_in[4];
  const float* Wt_b = (const float*)d_in[5];
  const float* Wa_w = (const float*)d_in[6];
  const float* Wa_b = (const float*)d_in[7];
  const float* Eh_w = (const float*)d_in[8];
  const float* Eh_b = (const float*)d_in[9];
  const float* Hw_w = (const float*)d_in[10];
  const float* Hw_b = (const float*)d_in[11];
  const float* Tr_w = (const float*)d_in[12];
  const float* Tr_b = (const float*)d_in[13];
  const float* Ei_w = (const float*)d_in[14];
  const float* Ei_b = (const float*)d_in[15];

  float* out_h  = (float*)d_out;
  float* out_ex = out_h + NEL;
  float* out_tm = out_ex + NEL;

  char* wsb = (char*)d_ws;
  float*    ws_ut  = (float*)(wsb);
  _Float16* ws_ab  = (_Float16*)(wsb + (16u << 20));
  _Float16* ws_ei  = (_Float16*)(wsb + (24u << 20));
  _Float16* ws_hup = (_Float16*)(wsb + (32u << 20));
  _Float16* ws_hw  = (_Float16*)(wsb + (40u << 20));
  _Float16* inpH   = (_Float16*)(wsb + (48u << 20));
  _Float16* hcH    = (_Float16*)(wsb + (56u << 20));
  _Float16* WtH    = (_Float16*)(wsb + (64u << 20));
  _Float16* TrH    = (_Float16*)(wsb + (68u << 20));
  _Float16* WaH    = (_Float16*)(wsb + (70u << 20));
  _Float16* HwH    = (_Float16*)(wsb + (74u << 20));
  _Float16* EhH    = (_Float16*)(wsb + (78u << 20));
  _Float16* EiH    = (_Float16*)(wsb + (82u << 20));
  int*      d_cnt  = (int*)(wsb + (84u << 20));
  int*      d_list = (int*)(wsb + (84u << 20) + 256);

  // Phase 0: f32 -> f16 planes (+ counter reset)
  convert_k<<<dim3(512, 1, 8), 256, 0, stream>>>(
      inp, hcur, Wt_w, Tr_w, Wa_w, Hw_w, Eh_w, Ei_w,
      inpH, hcH, WtH, TrH, WaH, HwH, EhH, EiH, d_cnt);

  // Phase 1: 5 GEMMs (heavy K=2048 first)
  qurnn_gemm5<<<dim3(256, 1, 5), 256, 0, stream>>>(
      inpH, hcH, WtH, Wt_b, WaH, Wa_b, HwH, Hw_b, TrH, Tr_b, EiH, Ei_b,
      ws_ut, ws_ab, ws_hw, out_tm, ws_ei);

  // Phase 2: elementwise cell update + LDS-compacted boundary flagging
  qurnn_cell<<<dim3(4096), 256, 0, stream>>>(
      (const f32x4*)tc, (const f32x4*)ec, (const f32x4*)hcur,
      (const f32x4*)ws_ut, (const half4*)ws_ab, (const half4*)ws_ei,
      (f32x4*)out_ex, (f32x4*)out_tm, (half4*)ws_hup, d_cnt, d_list);

  // Phase 3: exact recompute for leap-boundary elements
  qurnn_fixup<<<dim3(1024), 256, 0, stream>>>(
      d_cnt, d_list, inp, hcur, Tr_w, Tr_b, Wt_w, Wt_b,
      ws_ei, ws_ab, tc, ec, out_tm, out_ex, ws_hup);

  // Phase 4: Eh GEMM on [inp | h_up] + fused h_next epilogue
  qurnn_eh<<<dim3(256), 256, 0, stream>>>(
      inpH, ws_hup, EhH, Eh_b, ws_hw, hcur, out_h);
}